// Round 1
// baseline (718.311 us; speedup 1.0000x reference)
//
#include <hip/hip_runtime.h>

// RoI2Det: softmax -> threshold -> top-2000 -> class-aware greedy NMS -> top-100
// B=4 images, N=2000 proposals, C=80 fg classes (81 logits incl. background).
//
// Workspace layout (d_ws), requires 64 + B*CAP*8 = 262,208 bytes:
//   [0..63]    int counts[B] (zeroed via hipMemsetAsync each launch)
//   [64.. ]    u64 keys[B][CAP]  key = (score_bits<<32) | (0xFFFFFFFF - flat_idx)
//              -> sorting keys descending == lax.top_k order (score desc, idx asc on ties)

#define B_ 4
#define N_ 2000
#define C_ 80
#define NCLS 81
#define CAP 8192
#define KPRE 2000
#define MAXDET 100
#define SORT_P 8192

__device__ __forceinline__ unsigned long long pack_key(float score, unsigned fi) {
  return ((unsigned long long)__float_as_uint(score) << 32) |
         (unsigned long long)(0xFFFFFFFFu - fi);
}

// One wave (64 lanes) per proposal: softmax over 81 logits, threshold 0.05,
// append candidate keys to per-image list.
__global__ __launch_bounds__(256) void cand_kernel(
    const float* __restrict__ cls,
    unsigned long long* __restrict__ gkeys,
    int* __restrict__ gcnt) {
  int gt = blockIdx.x * 256 + (int)threadIdx.x;
  int wv = gt >> 6;
  int lane = threadIdx.x & 63;
  if (wv >= B_ * N_) return;
  int b = wv / N_;
  int n = wv - b * N_;
  const float* lg = cls + (size_t)wv * NCLS;
  float x0 = lg[lane];
  float x1 = (lane < NCLS - 64) ? lg[64 + lane] : -3.0e38f;
  float m = fmaxf(x0, x1);
#pragma unroll
  for (int o = 32; o > 0; o >>= 1) m = fmaxf(m, __shfl_xor(m, o));
  float e0 = expf(x0 - m);
  float e1 = (lane < NCLS - 64) ? expf(x1 - m) : 0.0f;
  float s = e0 + e1;
#pragma unroll
  for (int o = 32; o > 0; o >>= 1) s += __shfl_xor(s, o);
  // classes: lane -> c=lane (0..63), and c=64+lane for lane<16 (class 80 = background, dropped)
  float sc0 = e0 / s;
  if (sc0 > 0.05f) {
    int slot = atomicAdd(gcnt + b, 1);
    if (slot < CAP)
      gkeys[(size_t)b * CAP + slot] = pack_key(sc0, (unsigned)(n * C_ + lane));
  }
  if (lane < C_ - 64) {
    float sc1 = e1 / s;
    if (sc1 > 0.05f) {
      int slot = atomicAdd(gcnt + b, 1);
      if (slot < CAP)
        gkeys[(size_t)b * CAP + slot] = pack_key(sc1, (unsigned)(n * C_ + 64 + lane));
    }
  }
}

// One block per image: bitonic sort 8192 u64 keys in LDS, decode top-2000 boxes
// (with class offset baked in, as the reference does), greedy NMS with early
// exit at 100 kept, write detections.
__global__ __launch_bounds__(1024) void nms_kernel(
    const float* __restrict__ reg,
    const float* __restrict__ props,
    const int* __restrict__ hw,
    const unsigned long long* __restrict__ gkeys,
    const int* __restrict__ gcnt,
    float* __restrict__ out) {
  __shared__ unsigned long long keys[SORT_P];  // 64 KB, reused after sort
  const int b = blockIdx.x;
  const int tid = threadIdx.x;

  int M = gcnt[b];
  if (M > CAP) M = CAP;

  for (int t = tid; t < SORT_P; t += 1024)
    keys[t] = (t < M) ? gkeys[(size_t)b * CAP + t] : 0ULL;
  __syncthreads();

  // Bitonic sort, descending on u64 key (pads=0 sink to the end).
  for (int k = 2; k <= SORT_P; k <<= 1) {
    for (int j = k >> 1; j > 0; j >>= 1) {
      for (int t = tid; t < SORT_P / 2; t += 1024) {
        int i0 = ((t & ~(j - 1)) << 1) | (t & (j - 1));
        int i1 = i0 | j;
        unsigned long long a = keys[i0];
        unsigned long long c = keys[i1];
        bool desc = ((i0 & k) == 0);
        if ((a < c) == desc) { keys[i0] = c; keys[i1] = a; }
      }
      __syncthreads();
    }
  }

  int K = (M < KPRE) ? M : KPRE;
  // Pull my top-K keys to registers before the LDS region is repurposed.
  unsigned long long r0 = (tid < K) ? keys[tid] : 0ULL;
  unsigned long long r1 = (tid + 1024 < K) ? keys[tid + 1024] : 0ULL;
  __syncthreads();

  // Repurpose the 64 KB: [0:8000) scores, [8192:16192) labels, [16384:24384) keep,
  // [24576:24976) out list, [25088] next-idx scalar, [32768:64768) float4 boxes.
  char* basep = (char*)keys;
  float* s_sc = (float*)(basep);
  int* s_lab = (int*)(basep + 8192);
  int* s_keep = (int*)(basep + 16384);
  int* s_outl = (int*)(basep + 24576);
  int* s_next = (int*)(basep + 25088);
  float4* s_bx = (float4*)(basep + 32768);

  float h = (float)hw[b * 2 + 0];
  float w = (float)hw[b * 2 + 1];
  float offscale = fmaxf(h, w) + 1.0f;  // class-offset stride, as reference
  const float MAXR = 4.135166556742356f;  // |log(16/1000)|

#pragma unroll
  for (int r = 0; r < 2; ++r) {
    int j = tid + r * 1024;
    unsigned long long kk = r ? r1 : r0;
    if (j < K) {
      float score = __uint_as_float((unsigned)(kk >> 32));
      unsigned fi = 0xFFFFFFFFu - (unsigned)(kk & 0xFFFFFFFFull);
      int n = (int)(fi / (unsigned)C_);
      int c = (int)(fi - (unsigned)n * (unsigned)C_);
      float4 p = ((const float4*)props)[b * N_ + n];
      const float* dl = reg + ((size_t)(b * N_ + n)) * (C_ * 4) + c * 4;
      float dx = dl[0] * 0.1f;
      float dy = dl[1] * 0.1f;
      float dw = fminf(fmaxf(dl[2] * 0.2f, -MAXR), MAXR);
      float dh = fminf(fmaxf(dl[3] * 0.2f, -MAXR), MAXR);
      float px = (p.x + p.z) * 0.5f;
      float py = (p.y + p.w) * 0.5f;
      float pw = p.z - p.x;
      float ph = p.w - p.y;
      float gx = px + pw * dx;
      float gy = py + ph * dy;
      float gw = pw * expf(dw);
      float gh = ph * expf(dh);
      float off = (float)c * offscale;
      float x1v = fminf(fmaxf(gx - gw * 0.5f, 0.0f), w) + off;
      float y1v = fminf(fmaxf(gy - gh * 0.5f, 0.0f), h) + off;
      float x2v = fminf(fmaxf(gx + gw * 0.5f, 0.0f), w) + off;
      float y2v = fminf(fmaxf(gy + gh * 0.5f, 0.0f), h) + off;
      s_bx[j] = make_float4(x1v, y1v, x2v, y2v);
      s_sc[j] = score;
      s_lab[j] = c;
      s_keep[j] = 1;
    }
  }
  __syncthreads();

  // Greedy NMS over sorted candidates; early exit after MAXDET kept.
  // Offset boxes make cross-class IoU exactly 0 (min gap 1 unit >> fp32 ulp).
  int nkept = 0;
  if (K > 0) {
    int i = 0;
    while (true) {
      if (tid == 0) { s_outl[nkept] = i; s_next[0] = K; }
      nkept++;
      if (nkept >= MAXDET) break;
      __syncthreads();
      float4 bi = s_bx[i];
      float ai = (bi.z - bi.x) * (bi.w - bi.y);
      int localnext = K;
      for (int jj = i + 1 + tid; jj < K; jj += 1024) {
        if (!s_keep[jj]) continue;
        float4 bj = s_bx[jj];
        float aj = (bj.z - bj.x) * (bj.w - bj.y);
        float ix1 = fmaxf(bi.x, bj.x);
        float iy1 = fmaxf(bi.y, bj.y);
        float ix2 = fminf(bi.z, bj.z);
        float iy2 = fminf(bi.w, bj.w);
        float iw = fmaxf(ix2 - ix1, 0.0f);
        float ih = fmaxf(iy2 - iy1, 0.0f);
        float inter = iw * ih;
        float iou = inter / (ai + aj - inter + 1e-6f);
        if (iou > 0.5f) {
          s_keep[jj] = 0;
        } else if (jj < localnext) {
          localnext = jj;
        }
      }
      atomicMin(s_next, localnext);
      __syncthreads();
      int ni = s_next[0];
      __syncthreads();  // all threads read s_next before tid0 rewrites it
      if (ni >= K) break;
      i = ni;
    }
  }
  __syncthreads();

  // Outputs: boxes [B,100,4] | scores [B,100] | labels [B,100] (as float).
  float* oBox = out;
  float* oSc = out + B_ * MAXDET * 4;
  float* oLb = out + B_ * MAXDET * 5;
  for (int k2 = tid; k2 < MAXDET; k2 += 1024) {
    float4 bb = make_float4(0.0f, 0.0f, 0.0f, 0.0f);
    float sv = 0.0f, lv = -1.0f;
    if (k2 < nkept) {
      int idx = s_outl[k2];
      float off = (float)s_lab[idx] * offscale;
      float4 obx = s_bx[idx];
      bb = make_float4(obx.x - off, obx.y - off, obx.z - off, obx.w - off);
      sv = s_sc[idx];
      lv = (float)s_lab[idx];
    }
    oBox[(b * MAXDET + k2) * 4 + 0] = bb.x;
    oBox[(b * MAXDET + k2) * 4 + 1] = bb.y;
    oBox[(b * MAXDET + k2) * 4 + 2] = bb.z;
    oBox[(b * MAXDET + k2) * 4 + 3] = bb.w;
    oSc[b * MAXDET + k2] = sv;
    oLb[b * MAXDET + k2] = lv;
  }
}

extern "C" void kernel_launch(void* const* d_in, const int* in_sizes, int n_in,
                              void* d_out, int out_size, void* d_ws, size_t ws_size,
                              hipStream_t stream) {
  const float* cls = (const float*)d_in[0];    // [B,N,81] f32
  const float* reg = (const float*)d_in[1];    // [B,N,320] f32
  const float* props = (const float*)d_in[2];  // [B,N,4] f32
  const int* hw = (const int*)d_in[3];         // [B,2] i32
  float* out = (float*)d_out;                  // 2400 f32

  int* gcnt = (int*)d_ws;
  unsigned long long* gkeys = (unsigned long long*)((char*)d_ws + 64);

  hipMemsetAsync(d_ws, 0, 64, stream);  // zero per-image candidate counts

  int total_threads = B_ * N_ * 64;  // one wave per proposal
  cand_kernel<<<(total_threads + 255) / 256, 256, 0, stream>>>(cls, gkeys, gcnt);
  nms_kernel<<<B_, 1024, 0, stream>>>(reg, props, hw, gkeys, gcnt, out);
}

// Round 2
// 424.299 us; speedup vs baseline: 1.6929x; 1.6929x over previous
//
#include <hip/hip_runtime.h>

// RoI2Det: softmax -> threshold -> exact-top-prefix sort -> greedy NMS -> top-100
// B=4, N=2000 proposals, C=80 fg classes (81 logits incl background).
//
// Key insight: greedy NMS output = first 100 survivors of the score-ordered
// scan; candidates past the 100th survivor are irrelevant. We exactly sort
// only the top-S (S>=400) candidates selected via a score histogram; if NMS
// completes 100 keeps inside that prefix the result is provably identical to
// sorting everything. Fallback (full 8192 sort = R1's proven path) otherwise.
//
// Workspace: [0..63] int counts[B]; [64..] u64 keys[B][CAP].
// key = (score_bits<<32) | (0xFFFFFFFF - flat_idx)  -> desc sort == lax.top_k order.

typedef unsigned long long u64;
typedef unsigned int u32;

#define B_ 4
#define N_ 2000
#define C_ 80
#define NCLS 81
#define CAP 8192
#define KPRE 2000
#define MAXDET 100
#define TARGET 400      // sorted-prefix size floor (100th survivor ~ rank 130)
#define NB 2312         // score-histogram buckets
#define HBASE 0xF500    // (bits(0.05f))>>14 floor
#define KSHIFT 46       // key>>46 == score_bits>>14 (monotone in score)

__device__ __forceinline__ u64 pack_key(float score, unsigned fi) {
  return ((u64)__float_as_uint(score) << 32) | (u64)(0xFFFFFFFFu - fi);
}

// ---------------- candidate generation ----------------
// 1024 threads = 16 waves = 16 proposals/block; wave-ballot aggregation,
// ONE global atomicAdd per block (500 total vs ~16k per-lane before).
__global__ __launch_bounds__(1024) void cand_kernel(
    const float* __restrict__ cls, u64* __restrict__ gkeys, int* __restrict__ gcnt) {
  __shared__ int s_wc[16], s_woff[16], s_base;
  const int tid = threadIdx.x;
  const int w = tid >> 6, lane = tid & 63;
  const int bpi = N_ / 16;                 // 125 blocks per image (exact)
  const int b = blockIdx.x / bpi;
  const int n = (blockIdx.x % bpi) * 16 + w;
  const float* lg = cls + (size_t)(b * N_ + n) * NCLS;
  float x0 = lg[lane];
  float x1 = (lane < NCLS - 64) ? lg[64 + lane] : -3.0e38f;
  float mx = fmaxf(x0, x1);
#pragma unroll
  for (int o = 32; o > 0; o >>= 1) mx = fmaxf(mx, __shfl_xor(mx, o));
  float e0 = expf(x0 - mx);
  float e1 = (lane < NCLS - 64) ? expf(x1 - mx) : 0.0f;
  float sum = e0 + e1;
#pragma unroll
  for (int o = 32; o > 0; o >>= 1) sum += __shfl_xor(sum, o);
  float sc0 = e0 / sum, sc1 = e1 / sum;
  bool p0 = sc0 > 0.05f;
  bool p1 = (lane < C_ - 64) && (sc1 > 0.05f);   // class 80 = background: dropped
  u64 m0 = __ballot(p0), m1 = __ballot(p1);
  int c0 = __popcll(m0);
  if (lane == 0) s_wc[w] = c0 + __popcll(m1);
  __syncthreads();
  if (tid == 0) {
    int acc = 0;
#pragma unroll
    for (int i = 0; i < 16; ++i) { s_woff[i] = acc; acc += s_wc[i]; }
    s_base = atomicAdd(gcnt + b, acc);
  }
  __syncthreads();
  const int base = s_base + s_woff[w];
  const u64 lt = (1ull << lane) - 1;
  u64* gk = gkeys + (size_t)b * CAP;
  if (p0) {
    int slot = base + __popcll(m0 & lt);
    if (slot < CAP) gk[slot] = pack_key(sc0, (unsigned)(n * C_ + lane));
  }
  if (p1) {
    int slot = base + c0 + __popcll(m1 & lt);
    if (slot < CAP) gk[slot] = pack_key(sc1, (unsigned)(n * C_ + 64 + lane));
  }
}

// Bitonic sort, descending on u64 (0-pads sink to end). Uniform P per block.
__device__ __forceinline__ void bitonic_desc(u64* a, int P, int tid) {
  for (int k = 2; k <= P; k <<= 1) {
    for (int j = k >> 1; j > 0; j >>= 1) {
      for (int t = tid; t < (P >> 1); t += 1024) {
        int i0 = ((t & ~(j - 1)) << 1) | (t & (j - 1));
        int i1 = i0 | j;
        u64 x = a[i0], y = a[i1];
        bool desc = ((i0 & k) == 0);
        if ((x < y) == desc) { a[i0] = y; a[i1] = x; }
      }
      __syncthreads();
    }
  }
}

// Decode boxes for sorted prefix sh[0..K), greedy NMS, record outl. Returns
// nkept (uniform). LDS aliasing: sh[0..K<=2000) = bytes [0,16000) stays live;
// keep@16384, outl@24576, next@64768, bx@32768 only clobber dead sh regions.
__device__ __forceinline__ int decode_scan(
    u64* sh, int K, const float* __restrict__ reg, const float* __restrict__ props,
    int b, float h, float w, float offscale,
    int* s_keep, float4* s_bx, int* s_outl, int* s_next, int tid) {
  const float MAXR = 4.135166556742356f;  // |log(16/1000)|
  for (int j = tid; j < K; j += 1024) {
    u64 kk = sh[j];
    unsigned fi = 0xFFFFFFFFu - (u32)kk;
    int n = (int)(fi / (unsigned)C_);
    int c = (int)(fi - (unsigned)n * (unsigned)C_);
    float4 p = ((const float4*)props)[b * N_ + n];
    const float* dl = reg + ((size_t)(b * N_ + n)) * (C_ * 4) + c * 4;
    float dx = dl[0] * 0.1f;
    float dy = dl[1] * 0.1f;
    float dw = fminf(fmaxf(dl[2] * 0.2f, -MAXR), MAXR);
    float dh = fminf(fmaxf(dl[3] * 0.2f, -MAXR), MAXR);
    float px = (p.x + p.z) * 0.5f, py = (p.y + p.w) * 0.5f;
    float pw = p.z - p.x, ph = p.w - p.y;
    float gx = px + pw * dx, gy = py + ph * dy;
    float gw = pw * expf(dw), gh = ph * expf(dh);
    float off = (float)c * offscale;  // cross-class IoU exactly 0 after offset
    s_bx[j] = make_float4(fminf(fmaxf(gx - gw * 0.5f, 0.0f), w) + off,
                          fminf(fmaxf(gy - gh * 0.5f, 0.0f), h) + off,
                          fminf(fmaxf(gx + gw * 0.5f, 0.0f), w) + off,
                          fminf(fmaxf(gy + gh * 0.5f, 0.0f), h) + off);
    s_keep[j] = 1;
  }
  __syncthreads();
  int nkept = 0;
  if (K > 0) {
    int i = 0;
    while (true) {
      if (tid == 0) { s_outl[nkept] = i; s_next[0] = K; }
      nkept++;
      if (nkept >= MAXDET) break;
      __syncthreads();
      float4 bi4 = s_bx[i];
      float ai = (bi4.z - bi4.x) * (bi4.w - bi4.y);
      int localnext = K;
      for (int jj = i + 1 + tid; jj < K; jj += 1024) {
        if (!s_keep[jj]) continue;
        float4 bj = s_bx[jj];
        float aj = (bj.z - bj.x) * (bj.w - bj.y);
        float iw = fmaxf(fminf(bi4.z, bj.z) - fmaxf(bi4.x, bj.x), 0.0f);
        float ih = fmaxf(fminf(bi4.w, bj.w) - fmaxf(bi4.y, bj.y), 0.0f);
        float inter = iw * ih;
        float iou = inter / (ai + aj - inter + 1e-6f);
        if (iou > 0.5f) s_keep[jj] = 0;
        else if (jj < localnext) localnext = jj;
      }
      atomicMin(s_next, localnext);
      __syncthreads();
      int ni = s_next[0];
      __syncthreads();  // all read s_next before tid0 rewrites
      if (ni >= K) break;
      i = ni;
    }
  }
  __syncthreads();
  return nkept;
}

// One block per image.
__global__ __launch_bounds__(1024) void nms_kernel(
    const float* __restrict__ reg, const float* __restrict__ props,
    const int* __restrict__ hw, const u64* __restrict__ gkeys,
    const int* __restrict__ gcnt, float* __restrict__ out) {
  __shared__ u64 sh[CAP];  // 64 KB, time-multiplexed
  char* bp = (char*)sh;
  u32* hA = (u32*)(bp + 16384);      // hist ping [16384,25632)  (dead before keep/outl)
  u32* hB = (u32*)(bp + 25632);      // hist pong [25632,34880)  (dead before bx)
  int* s_keep = (int*)(bp + 16384);  // 2048 ints [16384,24576)
  int* s_outl = (int*)(bp + 24576);  // 100 ints
  float4* s_bx = (float4*)(bp + 32768);  // 2000 float4 [32768,64768)
  int* s_next = (int*)(bp + 64768);
  int* s_cnt = (int*)(bp + 64772);
  int* s_T = (int*)(bp + 64776);

  const int b = blockIdx.x, tid = threadIdx.x;
  const u64* gk = gkeys + (size_t)b * CAP;
  int M = gcnt[b];
  if (M > CAP) M = CAP;

  float h = (float)hw[b * 2 + 0];
  float w = (float)hw[b * 2 + 1];
  float offscale = fmaxf(h, w) + 1.0f;

  // Phase A: score-bucket histogram (keys read from global; sh untouched).
  for (int i = tid; i < NB; i += 1024) hA[i] = 0;
  __syncthreads();
  for (int t = tid; t < M; t += 1024) {
    int bi = (int)(gk[t] >> KSHIFT) - HBASE;
    bi = min(max(bi, 0), NB - 1);
    atomicAdd(&hA[bi], 1u);
  }
  __syncthreads();

  // Phase B: suffix-inclusive scan cum[i] = sum_{j>=i} hist[j] (12 passes).
  u32 *src = hA, *dst = hB;
  for (int d = 1; d < NB; d <<= 1) {
    for (int i = tid; i < NB; i += 1024) {
      u32 v = src[i];
      if (i + d < NB) v += src[i + d];
      dst[i] = v;
    }
    __syncthreads();
    u32* tmp = src; src = dst; dst = tmp;
  }

  // Phase C: threshold bucket T = max{i : cum[i] >= TARGET} (0 if M<TARGET).
  if (tid == 0) *s_T = 0;
  __syncthreads();
  for (int i = tid; i < NB; i += 1024)
    if (src[i] >= TARGET) atomicMax(s_T, i);
  __syncthreads();
  int T = *s_T;
  int S = (int)src[T];  // exact count of candidates in buckets >= T
  __syncthreads();

  int nkept = 0, K = 0;
  bool fullpath = (S > 2048);
  if (!fullpath) {
    // Phase D: compact top-S keys into sh[0..S) (order fixed by sort below).
    if (tid == 0) *s_cnt = 0;
    __syncthreads();
    for (int t = tid; t < M; t += 1024) {
      u64 key = gk[t];
      int bi = (int)(key >> KSHIFT) - HBASE;
      bi = min(max(bi, 0), NB - 1);
      if (bi >= T) { int p = atomicAdd(s_cnt, 1); sh[p] = key; }
    }
    __syncthreads();
    int P = 512;
    while (P < S) P <<= 1;  // 512/1024/2048
    for (int t = S + tid; t < P; t += 1024) sh[t] = 0;
    __syncthreads();
    bitonic_desc(sh, P, tid);  // exact order: score desc, index asc on ties
    K = (S < KPRE) ? S : KPRE;
    nkept = decode_scan(sh, K, reg, props, b, h, w, offscale,
                        s_keep, s_bx, s_outl, s_next, tid);
    // Exactness guarantee holds iff 100 keeps happened inside the prefix,
    // or the prefix already covers min(M, KPRE).
    if (nkept < MAXDET && S < M && S < KPRE) fullpath = true;
  }
  if (fullpath) {  // never taken in practice; exactness guard (R1's proven path)
    __syncthreads();
    for (int t = tid; t < CAP; t += 1024) sh[t] = (t < M) ? gk[t] : 0ULL;
    __syncthreads();
    bitonic_desc(sh, CAP, tid);
    K = (M < KPRE) ? M : KPRE;
    nkept = decode_scan(sh, K, reg, props, b, h, w, offscale,
                        s_keep, s_bx, s_outl, s_next, tid);
  }

  // Output: boxes [B,100,4] | scores [B,100] | labels [B,100] (as float).
  float* oBox = out;
  float* oSc = out + B_ * MAXDET * 4;
  float* oLb = out + B_ * MAXDET * 5;
  for (int k2 = tid; k2 < MAXDET; k2 += 1024) {
    float4 bb = make_float4(0.0f, 0.0f, 0.0f, 0.0f);
    float sv = 0.0f, lv = -1.0f;
    if (k2 < nkept) {
      int idx = s_outl[k2];
      u64 kk = sh[idx];  // idx < K <= 2000: bytes [0,16000), never clobbered
      sv = __uint_as_float((u32)(kk >> 32));
      unsigned fi = 0xFFFFFFFFu - (u32)kk;
      int c = (int)(fi % (unsigned)C_);
      float off = (float)c * offscale;
      float4 obx = s_bx[idx];
      bb = make_float4(obx.x - off, obx.y - off, obx.z - off, obx.w - off);
      lv = (float)c;
    }
    oBox[(b * MAXDET + k2) * 4 + 0] = bb.x;
    oBox[(b * MAXDET + k2) * 4 + 1] = bb.y;
    oBox[(b * MAXDET + k2) * 4 + 2] = bb.z;
    oBox[(b * MAXDET + k2) * 4 + 3] = bb.w;
    oSc[b * MAXDET + k2] = sv;
    oLb[b * MAXDET + k2] = lv;
  }
}

extern "C" void kernel_launch(void* const* d_in, const int* in_sizes, int n_in,
                              void* d_out, int out_size, void* d_ws, size_t ws_size,
                              hipStream_t stream) {
  const float* cls = (const float*)d_in[0];    // [B,N,81] f32
  const float* reg = (const float*)d_in[1];    // [B,N,320] f32
  const float* props = (const float*)d_in[2];  // [B,N,4] f32
  const int* hw = (const int*)d_in[3];         // [B,2] i32
  float* out = (float*)d_out;                  // 2400 f32

  int* gcnt = (int*)d_ws;
  u64* gkeys = (u64*)((char*)d_ws + 64);

  hipMemsetAsync(d_ws, 0, 64, stream);  // zero per-image candidate counts

  cand_kernel<<<B_ * N_ / 16, 1024, 0, stream>>>(cls, gkeys, gcnt);
  nms_kernel<<<B_, 1024, 0, stream>>>(reg, props, hw, gkeys, gcnt, out);
}

// Round 3
// 181.284 us; speedup vs baseline: 3.9624x; 2.3405x over previous
//
#include <hip/hip_runtime.h>

// RoI2Det: softmax -> threshold -> exact-top-prefix (histogram) -> rank-sort ->
// single-wave greedy NMS -> top-100.  B=4, N=2000, C=80 (81 logits w/ bg).
//
// Exactness: greedy NMS output depends only on the sorted prefix down to the
// 100th survivor. Normal path sorts the exact top-S (S in [400,512]) selected
// by a fine score histogram; if 100 keeps happen inside it, identical to the
// reference. Otherwise mode B rebuilds the exact top-2000 prefix (= reference's
// full lax.top_k(K_PRE) candidate set) and redoes NMS — exact by construction.
//
// Workspace: [0..63] int counts[B]; [64..] u64 keys[B][CAP].
// key = (score_bits<<32) | (0xFFFFFFFF - flat_idx): desc sort == lax.top_k order.

typedef unsigned long long u64;
typedef unsigned int u32;

#define B_ 4
#define N_ 2000
#define C_ 80
#define NCLS 81
#define CAP 8192
#define KPRE 2000
#define MAXDET 100
#define TARGET 400      // normal-path prefix floor (100th survivor ~ rank 130)
#define NB 2312         // score buckets: (bits>>14) - HBASE
#define HBASE 0xF500
#define KSHIFT 46       // key>>46 == score_bits>>14 (monotone in score)
#define CAPA 512        // single-wave NMS capacity
#define CAPB 2048       // escalated prefix capacity (>= 2000 + slack)

__device__ __forceinline__ u64 pack_key(float score, unsigned fi) {
  return ((u64)__float_as_uint(score) << 32) | (u64)(0xFFFFFFFFu - fi);
}

// ---------------- candidate generation (unchanged from R2) ----------------
__global__ __launch_bounds__(1024) void cand_kernel(
    const float* __restrict__ cls, u64* __restrict__ gkeys, int* __restrict__ gcnt) {
  __shared__ int s_wc[16], s_woff[16], s_base;
  const int tid = threadIdx.x;
  const int w = tid >> 6, lane = tid & 63;
  const int bpi = N_ / 16;  // 125 blocks per image
  const int b = blockIdx.x / bpi;
  const int n = (blockIdx.x % bpi) * 16 + w;
  const float* lg = cls + (size_t)(b * N_ + n) * NCLS;
  float x0 = lg[lane];
  float x1 = (lane < NCLS - 64) ? lg[64 + lane] : -3.0e38f;
  float mx = fmaxf(x0, x1);
#pragma unroll
  for (int o = 32; o > 0; o >>= 1) mx = fmaxf(mx, __shfl_xor(mx, o));
  float e0 = expf(x0 - mx);
  float e1 = (lane < NCLS - 64) ? expf(x1 - mx) : 0.0f;
  float sum = e0 + e1;
#pragma unroll
  for (int o = 32; o > 0; o >>= 1) sum += __shfl_xor(sum, o);
  float sc0 = e0 / sum, sc1 = e1 / sum;
  bool p0 = sc0 > 0.05f;
  bool p1 = (lane < C_ - 64) && (sc1 > 0.05f);  // class 80 = background
  u64 m0 = __ballot(p0), m1 = __ballot(p1);
  int c0 = __popcll(m0);
  if (lane == 0) s_wc[w] = c0 + __popcll(m1);
  __syncthreads();
  if (tid == 0) {
    int acc = 0;
#pragma unroll
    for (int i = 0; i < 16; ++i) { s_woff[i] = acc; acc += s_wc[i]; }
    s_base = atomicAdd(gcnt + b, acc);
  }
  __syncthreads();
  const int base = s_base + s_woff[w];
  const u64 lt = (1ull << lane) - 1;
  u64* gk = gkeys + (size_t)b * CAP;
  if (p0) {
    int slot = base + __popcll(m0 & lt);
    if (slot < CAP) gk[slot] = pack_key(sc0, (unsigned)(n * C_ + lane));
  }
  if (p1) {
    int slot = base + c0 + __popcll(m1 & lt);
    if (slot < CAP) gk[slot] = pack_key(sc1, (unsigned)(n * C_ + 64 + lane));
  }
}

// ---------------- per-image NMS kernel ----------------
// LDS map (60032 B static), by liveness:
//  [0,9248)      histA          (dead after scan/threshold)
//  [9248,18496)  histB          (dead after scan/threshold)
//  [18496,34880) U   u64[2048]  unsorted keys (dead after rank-scatter)
//  [34880,51264) SS  u64[2048]  sorted keys   (live to end)
//  [51264,59456) bxA float4[512]   mode A boxes  | keepB int[2048] (mode B)
//  [0,32000)     bxB float4[2000]  mode B boxes (over dead hist+U)
//  [59456,59968) outl int[128];  [59968,60032) misc int[16]
// misc: 0=T_A 1=T_B 2=S_A 3=S_B 4=cnt 5=next 6=nkept

__device__ __forceinline__ float4 decode_one(
    u64 kk, const float* __restrict__ reg, const float* __restrict__ props,
    int b, float h, float w, float offscale) {
  const float MAXR = 4.135166556742356f;  // |log(16/1000)|
  unsigned fi = 0xFFFFFFFFu - (u32)kk;
  int n = (int)(fi / (unsigned)C_);
  int c = (int)(fi - (unsigned)n * (unsigned)C_);
  float4 p = ((const float4*)props)[b * N_ + n];
  const float* dl = reg + ((size_t)(b * N_ + n)) * (C_ * 4) + c * 4;
  float dx = dl[0] * 0.1f;
  float dy = dl[1] * 0.1f;
  float dw = fminf(fmaxf(dl[2] * 0.2f, -MAXR), MAXR);
  float dh = fminf(fmaxf(dl[3] * 0.2f, -MAXR), MAXR);
  float px = (p.x + p.z) * 0.5f, py = (p.y + p.w) * 0.5f;
  float pw = p.z - p.x, ph = p.w - p.y;
  float gx = px + pw * dx, gy = py + ph * dy;
  float gw = pw * expf(dw), gh = ph * expf(dh);
  float off = (float)c * offscale;  // cross-class IoU exactly 0 after offset
  return make_float4(fminf(fmaxf(gx - gw * 0.5f, 0.0f), w) + off,
                     fminf(fmaxf(gy - gh * 0.5f, 0.0f), h) + off,
                     fminf(fmaxf(gx + gw * 0.5f, 0.0f), w) + off,
                     fminf(fmaxf(gy + gh * 0.5f, 0.0f), h) + off);
}

__global__ __launch_bounds__(1024) void nms_kernel(
    const float* __restrict__ reg, const float* __restrict__ props,
    const int* __restrict__ hw, const u64* __restrict__ gkeys,
    const int* __restrict__ gcnt, float* __restrict__ out) {
  __shared__ u64 lds8[7504];  // 60032 B
  char* bp = (char*)lds8;
  u32* hA = (u32*)(bp + 0);
  u32* hB = (u32*)(bp + 9248);
  u64* U = (u64*)(bp + 18496);
  u64* SS = (u64*)(bp + 34880);
  float4* bxA = (float4*)(bp + 51264);
  float4* bxB = (float4*)(bp + 0);
  int* keepB = (int*)(bp + 51264);
  int* outl = (int*)(bp + 59456);
  int* misc = (int*)(bp + 59968);

  const int b = blockIdx.x, tid = threadIdx.x;
  const u64* gk = gkeys + (size_t)b * CAP;
  int M = gcnt[b];
  if (M > CAP) M = CAP;
  float h = (float)hw[b * 2 + 0];
  float w = (float)hw[b * 2 + 1];
  float offscale = fmaxf(h, w) + 1.0f;

  if (tid < 16) misc[tid] = 0;
  for (int i = tid; i < NB; i += 1024) hA[i] = 0;
  __syncthreads();

  // Histogram of score buckets.
  for (int t = tid; t < M; t += 1024) {
    int bi = (int)(gk[t] >> KSHIFT) - HBASE;
    bi = min(max(bi, 0), NB - 1);
    atomicAdd(&hA[bi], 1u);
  }
  __syncthreads();

  // Suffix-inclusive scan (12 passes; ends back in hA).
  u32 *src = hA, *dst = hB;
  for (int d = 1; d < NB; d <<= 1) {
    for (int i = tid; i < NB; i += 1024) {
      u32 v = src[i];
      if (i + d < NB) v += src[i + d];
      dst[i] = v;
    }
    __syncthreads();
    u32* tmp = src; src = dst; dst = tmp;
  }

  // Thresholds: T_A (>=TARGET), T_B (>=KPRE). Saved now; hist dies after.
  for (int i = tid; i < NB; i += 1024) {
    u32 v = src[i];
    if (v >= (u32)TARGET) atomicMax(&misc[0], i);
    if (v >= (u32)KPRE) atomicMax(&misc[1], i);
  }
  __syncthreads();
  if (tid == 0) {
    int TA = misc[0], TB = misc[1];
    int SB = (int)src[TB];
    if (SB > CAPB && TB + 1 < NB) {  // fat-bucket guard; unreachable in practice
      TB++; SB = (int)src[TB]; misc[1] = TB;
    }
    misc[2] = (int)src[TA];
    misc[3] = SB;
  }
  __syncthreads();
  int TA = misc[0], SA = misc[2];
  bool modeB = (SA > CAPA);
  int K = 0, nkept = 0;

  if (!modeB) {
    // Compact bucket>=TA into U (unordered; rank-scatter fixes order).
    if (tid == 0) misc[4] = 0;
    __syncthreads();
    for (int t = tid; t < M; t += 1024) {
      u64 key = gk[t];
      int bi = (int)(key >> KSHIFT) - HBASE;
      bi = min(max(bi, 0), NB - 1);
      if (bi >= TA) { int p = atomicAdd(&misc[4], 1); if (p < CAPA) U[p] = key; }
    }
    __syncthreads();
    int S = misc[4]; if (S > CAPA) S = CAPA;
    // Rank-scatter sort: keys distinct (unique flat idx) -> perfect permutation.
    {
      u64 k1 = (tid < S) ? U[tid] : 0ULL;
      int r1 = 0;
      for (int k = 0; k < S; k++) r1 += (U[k] > k1);  // LDS broadcast sweep
      __syncthreads();
      if (tid < S) SS[r1] = k1;
    }
    __syncthreads();
    K = S;  // S <= 512 < KPRE
    for (int j = tid; j < K; j += 1024)
      bxA[j] = decode_one(SS[j], reg, props, b, h, w, offscale);
    __syncthreads();

    // Single-wave NMS: boxes in registers, alive bitmask, zero barriers/atomics.
    if (tid < 64) {
      const int lane = tid;
      float4 bx[8];
      unsigned alive = 0;
#pragma unroll
      for (int r = 0; r < 8; r++) {
        int j = (r << 6) | lane;
        if (j < K) { bx[r] = bxA[j]; alive |= 1u << r; }
      }
      int nk = 0;
      if (K > 0) {
        int i = 0;
        for (;;) {
          if (lane == 0) outl[nk] = i;
          nk++;
          if (nk >= MAXDET) break;
          float4 tb = bxA[i];  // uniform address -> LDS broadcast
          float ai = (tb.z - tb.x) * (tb.w - tb.y);
          int best = K;
#pragma unroll
          for (int r = 0; r < 8; r++) {
            int j = (r << 6) | lane;
            if ((alive >> r & 1u) && j > i) {
              float4 bj = bx[r];
              float aj = (bj.z - bj.x) * (bj.w - bj.y);
              float iw = fmaxf(fminf(tb.z, bj.z) - fmaxf(tb.x, bj.x), 0.0f);
              float ih = fmaxf(fminf(tb.w, bj.w) - fmaxf(tb.y, bj.y), 0.0f);
              float inter = iw * ih;
              float iou = inter / (ai + aj - inter + 1e-6f);
              if (iou > 0.5f) alive &= ~(1u << r);
              else best = min(best, j);
            }
          }
#pragma unroll
          for (int off = 32; off; off >>= 1) best = min(best, __shfl_xor(best, off));
          if (best >= K) break;
          i = best;
        }
      }
      if (lane == 0) misc[6] = nk;
    }
    __syncthreads();
    nkept = misc[6];
    // Exactness guard: escalate iff <100 keeps and prefix didn't cover min(M,KPRE).
    if (nkept < MAXDET && K < M && K < KPRE) modeB = true;
  }

  if (modeB) {
    __syncthreads();
    int TB = misc[1];
    if (tid == 0) misc[4] = 0;
    __syncthreads();
    for (int t = tid; t < M; t += 1024) {
      u64 key = gk[t];
      int bi = (int)(key >> KSHIFT) - HBASE;
      bi = min(max(bi, 0), NB - 1);
      if (bi >= TB) { int p = atomicAdd(&misc[4], 1); if (p < CAPB) U[p] = key; }
    }
    __syncthreads();
    int S = misc[4]; if (S > CAPB) S = CAPB;
    {
      int j1 = tid, j2 = tid + 1024;
      u64 k1 = (j1 < S) ? U[j1] : 0ULL;
      u64 k2 = (j2 < S) ? U[j2] : 0ULL;
      int r1 = 0, r2 = 0;
      for (int k = 0; k < S; k++) { u64 kk = U[k]; r1 += (kk > k1); r2 += (kk > k2); }
      __syncthreads();
      if (j1 < S) SS[r1] = k1;
      if (j2 < S) SS[r2] = k2;
    }
    __syncthreads();
    K = (S < KPRE) ? S : KPRE;  // exact top-2000 (or all M if fewer)
    for (int j = tid; j < K; j += 1024) {
      bxB[j] = decode_one(SS[j], reg, props, b, h, w, offscale);
      keepB[j] = 1;
    }
    __syncthreads();
    // Multi-wave NMS with per-wave reduced atomicMin (16 atomics/iter, not 1024).
    int nk = 0;
    if (K > 0) {
      int i = 0;
      for (;;) {
        if (tid == 0) { outl[nk] = i; misc[5] = K; }
        nk++;
        if (nk >= MAXDET) break;
        __syncthreads();
        float4 tb = bxB[i];
        float ai = (tb.z - tb.x) * (tb.w - tb.y);
        int ln = K;
        for (int jj = i + 1 + tid; jj < K; jj += 1024) {
          if (!keepB[jj]) continue;
          float4 bj = bxB[jj];
          float aj = (bj.z - bj.x) * (bj.w - bj.y);
          float iw = fmaxf(fminf(tb.z, bj.z) - fmaxf(tb.x, bj.x), 0.0f);
          float ih = fmaxf(fminf(tb.w, bj.w) - fmaxf(tb.y, bj.y), 0.0f);
          float inter = iw * ih;
          float iou = inter / (ai + aj - inter + 1e-6f);
          if (iou > 0.5f) keepB[jj] = 0;
          else ln = min(ln, jj);
        }
#pragma unroll
        for (int off = 32; off; off >>= 1) ln = min(ln, __shfl_xor(ln, off));
        if ((tid & 63) == 0 && ln < K) atomicMin(&misc[5], ln);
        __syncthreads();
        int ni = misc[5];
        __syncthreads();  // all read before tid0 rewrites at loop top
        if (ni >= K) break;
        i = ni;
      }
    }
    if (tid == 0) misc[6] = nk;
    __syncthreads();
    nkept = misc[6];
  }

  // Output: boxes [B,100,4] | scores [B,100] | labels [B,100] (as float).
  float4* bx = modeB ? bxB : bxA;
  float* oBox = out;
  float* oSc = out + B_ * MAXDET * 4;
  float* oLb = out + B_ * MAXDET * 5;
  for (int k2 = tid; k2 < MAXDET; k2 += 1024) {
    float4 bb = make_float4(0.0f, 0.0f, 0.0f, 0.0f);
    float sv = 0.0f, lv = -1.0f;
    if (k2 < nkept) {
      int idx = outl[k2];
      u64 kk = SS[idx];
      sv = __uint_as_float((u32)(kk >> 32));
      unsigned fi = 0xFFFFFFFFu - (u32)kk;
      int c = (int)(fi % (unsigned)C_);
      float off = (float)c * offscale;
      float4 ob = bx[idx];
      bb = make_float4(ob.x - off, ob.y - off, ob.z - off, ob.w - off);
      lv = (float)c;
    }
    oBox[(b * MAXDET + k2) * 4 + 0] = bb.x;
    oBox[(b * MAXDET + k2) * 4 + 1] = bb.y;
    oBox[(b * MAXDET + k2) * 4 + 2] = bb.z;
    oBox[(b * MAXDET + k2) * 4 + 3] = bb.w;
    oSc[b * MAXDET + k2] = sv;
    oLb[b * MAXDET + k2] = lv;
  }
}

extern "C" void kernel_launch(void* const* d_in, const int* in_sizes, int n_in,
                              void* d_out, int out_size, void* d_ws, size_t ws_size,
                              hipStream_t stream) {
  const float* cls = (const float*)d_in[0];    // [B,N,81] f32
  const float* reg = (const float*)d_in[1];    // [B,N,320] f32
  const float* props = (const float*)d_in[2];  // [B,N,4] f32
  const int* hw = (const int*)d_in[3];         // [B,2] i32
  float* out = (float*)d_out;                  // 2400 f32

  int* gcnt = (int*)d_ws;
  u64* gkeys = (u64*)((char*)d_ws + 64);

  hipMemsetAsync(d_ws, 0, 64, stream);  // zero per-image candidate counts

  cand_kernel<<<B_ * N_ / 16, 1024, 0, stream>>>(cls, gkeys, gcnt);
  nms_kernel<<<B_, 1024, 0, stream>>>(reg, props, hw, gkeys, gcnt, out);
}